// Round 6
// baseline (4106.273 us; speedup 1.0000x reference)
//
#include <hip/hip_runtime.h>
#include <hip/hip_bf16.h>
#include <math.h>

#define N_OBJ 4096
#define IN_DIM 1024
#define EMB_D 200
#define HID 1024
#define NCLS 151
#define NCPAD 160       // NCLS padded to 10 MFMA col-frags
#define IN_SZ 1224      // IN_DIM + EMB_D
#define NEMB 152        // NCLS + 1 embedding rows
#define R5 5120         // px(1024) + iou(3072) + f(1024) pre-activation rows
#define RH 4096         // h-dependent rows (iou 3072 + f 1024)
#define MAXLVL 32

typedef __attribute__((ext_vector_type(8))) short bf16x8;
typedef __attribute__((ext_vector_type(4))) float f32x4;

__device__ __forceinline__ float sigf(float x) { return 1.f / (1.f + expf(-x)); }

// split fp32 into hi+lo bf16 (RNE both stages); hi+lo carries ~18 mantissa bits
__device__ __forceinline__ void split2(float x, ushort& hi, ushort& lo) {
    unsigned u = __float_as_uint(x);
    unsigned r = u + 0x7FFFu + ((u >> 16) & 1u);
    hi = (ushort)(r >> 16);
    float rem = x - __uint_as_float(r & 0xFFFF0000u);
    unsigned u2 = __float_as_uint(rem);
    unsigned r2 = u2 + 0x7FFFu + ((u2 >> 16) & 1u);
    lo = (ushort)(r2 >> 16);
}

// ---------------------------------------------------------------------------
// Kernel 1: depth per step, bucket steps by level; also zero zpad.
// ---------------------------------------------------------------------------
__global__ __launch_bounds__(1024)
void build_levels(const int* __restrict__ parent_pos,
                  int* __restrict__ level_nodes,
                  int* __restrict__ level_start,
                  ushort* __restrict__ zpad)
{
    __shared__ int dep[N_OBJ];
    __shared__ int par[N_OBJ];
    __shared__ int cnt[MAXLVL];
    __shared__ int offs[MAXLVL];
    __shared__ int base[MAXLVL + 1];
    __shared__ int done;
    const int tid = threadIdx.x;

    if (tid < 1024) zpad[tid] = 0;

    for (int t = tid; t < N_OBJ; t += 1024) {
        int p = parent_pos[t];
        par[t] = p;
        dep[t] = (p < 0) ? 0 : -1;
    }
    for (int l = tid; l < MAXLVL; l += 1024) { cnt[l] = 0; offs[l] = 0; }
    __syncthreads();

    for (int it = 0; it < 64; ++it) {
        if (tid == 0) done = 1;
        __syncthreads();
        for (int t = tid; t < N_OBJ; t += 1024) {
            if (dep[t] < 0) {
                int dp = dep[par[t]];
                if (dp >= 0) dep[t] = dp + 1;
                else done = 0;
            }
        }
        __syncthreads();
        int d = done;
        __syncthreads();
        if (d) break;
    }

    for (int t = tid; t < N_OBJ; t += 1024) {
        int d = dep[t];
        if (d < 0 || d >= MAXLVL) d = MAXLVL - 1;  // safety clamp
        dep[t] = d;
        atomicAdd(&cnt[d], 1);
    }
    __syncthreads();
    if (tid == 0) {
        base[0] = 0;
        for (int l = 0; l < MAXLVL; ++l) base[l + 1] = base[l] + cnt[l];
    }
    __syncthreads();
    for (int t = tid; t < N_OBJ; t += 1024) {
        int d = dep[t];
        int pos = base[d] + atomicAdd(&offs[d], 1);
        level_nodes[pos] = t;
    }
    for (int l = tid; l <= MAXLVL; l += 1024) level_start[l] = base[l];
}

// ---------------------------------------------------------------------------
// Kernel 2: Xemb[e][r] = W_row_r[:, 1024:1224] @ embed_W[e] + (all biases)
// ---------------------------------------------------------------------------
__global__ __launch_bounds__(256)
void xemb_kernel(const float* __restrict__ embed_W,
                 const float* __restrict__ W_px,
                 const float* __restrict__ W_ioux,
                 const float* __restrict__ W_fx,
                 const float* __restrict__ b_px,
                 const float* __restrict__ b_ioux,
                 const float* __restrict__ b_iouh,
                 const float* __restrict__ b_fx,
                 const float* __restrict__ b_fh,
                 float* __restrict__ Xemb)
{
    __shared__ float e_s[EMB_D];
    const int e = blockIdx.x;
    const int r = blockIdx.y * 256 + threadIdx.x;
    for (int k = threadIdx.x; k < EMB_D; k += 256) e_s[k] = embed_W[(size_t)e * EMB_D + k];
    __syncthreads();

    const float* wrow;
    float bias;
    if (r < HID) {
        wrow = W_px + (size_t)r * IN_SZ;
        bias = b_px[r];
    } else if (r < 4 * HID) {
        wrow = W_ioux + (size_t)(r - HID) * IN_SZ;
        bias = b_ioux[r - HID] + b_iouh[r - HID];
    } else {
        wrow = W_fx + (size_t)(r - 4 * HID) * IN_SZ;
        bias = b_fx[r - 4 * HID] + b_fh[r - 4 * HID];
    }

    float s = bias;
    for (int k = 0; k < EMB_D; ++k) s += wrow[IN_DIM + k] * e_s[k];
    Xemb[(size_t)e * R5 + r] = s;
}

// ---------------------------------------------------------------------------
// One-time split-conversion kernels (fp32 -> hi/lo bf16 pairs)
// ---------------------------------------------------------------------------
__global__ __launch_bounds__(256)
void convert_wh(const float* __restrict__ W_iouh, const float* __restrict__ W_fh,
                ushort* __restrict__ Whh, ushort* __restrict__ Whl)
{
    const int idx = (blockIdx.x * 256 + threadIdx.x) * 4;
    const int row = idx >> 10, k = idx & 1023;
    const float* src = (row < 3 * HID) ? (W_iouh + (size_t)row * HID + k)
                                       : (W_fh + (size_t)(row - 3 * HID) * HID + k);
    float4 v = *(const float4*)src;
    ushort4 hi, lo;
    split2(v.x, hi.x, lo.x); split2(v.y, hi.y, lo.y);
    split2(v.z, hi.z, lo.z); split2(v.w, hi.w, lo.w);
    *(ushort4*)(Whh + (size_t)row * HID + k) = hi;
    *(ushort4*)(Whl + (size_t)row * HID + k) = lo;
}

__global__ __launch_bounds__(256)
void convert_wx(const float* __restrict__ W_px, const float* __restrict__ W_ioux,
                const float* __restrict__ W_fx,
                ushort* __restrict__ Wxh, ushort* __restrict__ Wxl)
{
    const int idx = (blockIdx.x * 256 + threadIdx.x) * 4;
    const int row = idx >> 10, k = idx & 1023;
    const float* src;
    if (row < HID)          src = W_px   + (size_t)row * IN_SZ + k;
    else if (row < 4 * HID) src = W_ioux + (size_t)(row - HID) * IN_SZ + k;
    else                    src = W_fx   + (size_t)(row - 4 * HID) * IN_SZ + k;
    float4 v = *(const float4*)src;
    ushort4 hi, lo;
    split2(v.x, hi.x, lo.x); split2(v.y, hi.y, lo.y);
    split2(v.z, hi.z, lo.z); split2(v.w, hi.w, lo.w);
    *(ushort4*)(Wxh + (size_t)row * IN_DIM + k) = hi;
    *(ushort4*)(Wxl + (size_t)row * IN_DIM + k) = lo;
}

__global__ __launch_bounds__(256)
void convert_f(const float* __restrict__ features, const int* __restrict__ proc_order,
               ushort* __restrict__ Fh, ushort* __restrict__ Fl)
{
    const int idx = (blockIdx.x * 256 + threadIdx.x) * 4;
    const int t = idx >> 10, k = idx & 1023;
    const float* src = features + (size_t)proc_order[t] * IN_DIM + k;
    float4 v = *(const float4*)src;
    ushort4 hi, lo;
    split2(v.x, hi.x, lo.x); split2(v.y, hi.y, lo.y);
    split2(v.z, hi.z, lo.z); split2(v.w, hi.w, lo.w);
    *(ushort4*)(Fh + (size_t)t * IN_DIM + k) = hi;
    *(ushort4*)(Fl + (size_t)t * IN_DIM + k) = lo;
}

// W_out -> padded [NCPAD][HID] split pair (rows >= NCLS zeroed)
__global__ __launch_bounds__(256)
void convert_wout(const float* __restrict__ W_out,
                  ushort* __restrict__ Woh, ushort* __restrict__ Wol)
{
    const int idx = (blockIdx.x * 256 + threadIdx.x) * 4;
    const int row = idx >> 10, k = idx & 1023;
    float4 v = make_float4(0.f, 0.f, 0.f, 0.f);
    if (row < NCLS) v = *(const float4*)(W_out + (size_t)row * HID + k);
    ushort4 hi, lo;
    split2(v.x, hi.x, lo.x); split2(v.y, hi.y, lo.y);
    split2(v.z, hi.z, lo.z); split2(v.w, hi.w, lo.w);
    *(ushort4*)(Woh + (size_t)row * HID + k) = hi;
    *(ushort4*)(Wol + (size_t)row * HID + k) = lo;
}

// ---------------------------------------------------------------------------
// Kernel 3 (ONCE): x-part GEMM via split-bf16 MFMA, coalesced LDS epilogue.
// __launch_bounds__(256,2): LDS caps at 2 blocks/CU anyway -> 256-VGPR budget,
// avoids the round-4/5 spill (VGPR 104 + 1.3 GB scratch writes).
// ---------------------------------------------------------------------------
__global__ __launch_bounds__(256, 2)
void xgemm_mfma(const ushort* __restrict__ Fh, const ushort* __restrict__ Fl,
                const ushort* __restrict__ Wxh, const ushort* __restrict__ Wxl,
                float* __restrict__ Hbuf)
{
    const int bid = blockIdx.x;
    const int sup = bid >> 6, within = bid & 63;
    const int bm = (sup & 3) * 8 + (within & 7);
    const int bn = (sup >> 2) * 8 + (within >> 3);

    __shared__ __align__(16) ushort smem[4 * 128 * 72];   // 73728 B
    ushort* Ah = smem;
    ushort* Al = smem + 128 * 72;
    ushort* Bh = smem + 2 * 128 * 72;
    ushort* Bl = smem + 3 * 128 * 72;

    const int tid = threadIdx.x;
    const int lane = tid & 63;
    const int wid = tid >> 6;
    const int wm = wid & 1, wn = wid >> 1;

    const int srow = tid >> 1, skq = tid & 1;
    const ushort* gAh = Fh  + (size_t)(bm * 128 + srow) * IN_DIM + skq * 32;
    const ushort* gAl = Fl  + (size_t)(bm * 128 + srow) * IN_DIM + skq * 32;
    const ushort* gBh = Wxh + (size_t)(bn * 128 + srow) * IN_DIM + skq * 32;
    const ushort* gBl = Wxl + (size_t)(bn * 128 + srow) * IN_DIM + skq * 32;

    f32x4 acc[4][4];
    #pragma unroll
    for (int i = 0; i < 4; ++i)
        #pragma unroll
        for (int j = 0; j < 4; ++j)
            acc[i][j] = (f32x4){0.f, 0.f, 0.f, 0.f};

    uint4 rA0[4], rA1[4], rB0[4], rB1[4];
    #pragma unroll
    for (int j = 0; j < 4; ++j) {
        rA0[j] = *(const uint4*)(gAh + j * 8);
        rA1[j] = *(const uint4*)(gAl + j * 8);
        rB0[j] = *(const uint4*)(gBh + j * 8);
        rB1[j] = *(const uint4*)(gBl + j * 8);
    }

    for (int kc = 0; kc < IN_DIM / 64; ++kc) {
        __syncthreads();
        #pragma unroll
        for (int j = 0; j < 4; ++j) {
            *(uint4*)&Ah[srow * 72 + skq * 32 + j * 8] = rA0[j];
            *(uint4*)&Al[srow * 72 + skq * 32 + j * 8] = rA1[j];
            *(uint4*)&Bh[srow * 72 + skq * 32 + j * 8] = rB0[j];
            *(uint4*)&Bl[srow * 72 + skq * 32 + j * 8] = rB1[j];
        }
        __syncthreads();
        if (kc + 1 < IN_DIM / 64) {
            const int kt = (kc + 1) * 64;
            #pragma unroll
            for (int j = 0; j < 4; ++j) {
                rA0[j] = *(const uint4*)(gAh + kt + j * 8);
                rA1[j] = *(const uint4*)(gAl + kt + j * 8);
                rB0[j] = *(const uint4*)(gBh + kt + j * 8);
                rB1[j] = *(const uint4*)(gBl + kt + j * 8);
            }
        }
        const int g = lane >> 4;
        #pragma unroll
        for (int s = 0; s < 2; ++s) {
            bf16x8 fah[4], fal[4], fbh[4], fbl[4];
            #pragma unroll
            for (int mi = 0; mi < 4; ++mi) {
                int o = (wm * 64 + mi * 16 + (lane & 15)) * 72 + s * 32 + g * 8;
                fah[mi] = *(const bf16x8*)&Ah[o];
                fal[mi] = *(const bf16x8*)&Al[o];
            }
            #pragma unroll
            for (int ni = 0; ni < 4; ++ni) {
                int o = (wn * 64 + ni * 16 + (lane & 15)) * 72 + s * 32 + g * 8;
                fbh[ni] = *(const bf16x8*)&Bh[o];
                fbl[ni] = *(const bf16x8*)&Bl[o];
            }
            #pragma unroll
            for (int mi = 0; mi < 4; ++mi)
                #pragma unroll
                for (int ni = 0; ni < 4; ++ni) {
                    acc[mi][ni] = __builtin_amdgcn_mfma_f32_16x16x32_bf16(fah[mi], fbh[ni], acc[mi][ni], 0, 0, 0);
                    acc[mi][ni] = __builtin_amdgcn_mfma_f32_16x16x32_bf16(fah[mi], fbl[ni], acc[mi][ni], 0, 0, 0);
                    acc[mi][ni] = __builtin_amdgcn_mfma_f32_16x16x32_bf16(fal[mi], fbh[ni], acc[mi][ni], 0, 0, 0);
                }
        }
    }

    // epilogue: LDS transpose -> coalesced float4 row writes
    __syncthreads();
    float* Cs = (float*)smem;   // [128][132] = 67584 B
    const int r4 = (lane >> 4) * 4;
    #pragma unroll
    for (int mi = 0; mi < 4; ++mi)
        #pragma unroll
        for (int ni = 0; ni < 4; ++ni) {
            const int col = wn * 64 + ni * 16 + (lane & 15);
            const int row = wm * 64 + mi * 16 + r4;
            #pragma unroll
            for (int r = 0; r < 4; ++r)
                Cs[(row + r) * 132 + col] = acc[mi][ni][r];
        }
    __syncthreads();
    const int t0 = bm * 128, c0 = bn * 128;
    #pragma unroll
    for (int i = 0; i < 16; ++i) {
        int row = i * 8 + (tid >> 5);
        float4 v = *(const float4*)&Cs[row * 132 + (tid & 31) * 4];
        *(float4*)&Hbuf[(size_t)(t0 + row) * R5 + c0 + (tid & 31) * 4] = v;
    }
}

// ---------------------------------------------------------------------------
// Kernel 4 (per level): Hbuf[t][1024+r] += Wh_r . h[parent(t)]
// 128x128 tile (same structure as xgemm), grid dim3(8,32) with bm-loop.
// ---------------------------------------------------------------------------
__global__ __launch_bounds__(256, 2)
void hgemm_mfma(int lvl,
                const int* __restrict__ level_start,
                const int* __restrict__ level_nodes,
                const int* __restrict__ parent_pos,
                const ushort* __restrict__ hh, const ushort* __restrict__ hl,
                const ushort* __restrict__ Whh, const ushort* __restrict__ Whl,
                const ushort* __restrict__ zpad,
                float* __restrict__ Hbuf)
{
    const int s0 = level_start[lvl];
    const int n  = level_start[lvl + 1] - s0;
    const int bn = blockIdx.y;
    const int tid = threadIdx.x;
    const int lane = tid & 63;
    const int wid = tid >> 6;
    const int wm = wid & 1, wn = wid >> 1;

    __shared__ __align__(16) ushort smem[4 * 128 * 72];   // 73728 B
    ushort* Ah = smem;
    ushort* Al = smem + 128 * 72;
    ushort* Bh = smem + 2 * 128 * 72;
    ushort* Bl = smem + 3 * 128 * 72;
    __shared__ int s_node[128], s_par[128];

    const int srow = tid >> 1, skq = tid & 1;
    const ushort* gBh = Whh + (size_t)(bn * 128 + srow) * HID + skq * 32;
    const ushort* gBl = Whl + (size_t)(bn * 128 + srow) * HID + skq * 32;

    for (int bm = blockIdx.x; bm * 128 < n; bm += gridDim.x) {
        __syncthreads();   // protect s_node/Cs reuse from previous iteration
        if (tid < 128) {
            int m = bm * 128 + tid;
            if (m < n) {
                int t = level_nodes[s0 + m];
                s_node[tid] = t;
                s_par[tid]  = parent_pos[t];
            } else { s_node[tid] = -1; s_par[tid] = -1; }
        }
        __syncthreads();

        const int par = s_par[srow];
        const ushort* gAh = (par >= 0 ? hh + (size_t)par * HID : zpad) + skq * 32;
        const ushort* gAl = (par >= 0 ? hl + (size_t)par * HID : zpad) + skq * 32;

        f32x4 acc[4][4];
        #pragma unroll
        for (int i = 0; i < 4; ++i)
            #pragma unroll
            for (int j = 0; j < 4; ++j)
                acc[i][j] = (f32x4){0.f, 0.f, 0.f, 0.f};

        uint4 rA0[4], rA1[4], rB0[4], rB1[4];
        #pragma unroll
        for (int j = 0; j < 4; ++j) {
            rA0[j] = *(const uint4*)(gAh + j * 8);
            rA1[j] = *(const uint4*)(gAl + j * 8);
            rB0[j] = *(const uint4*)(gBh + j * 8);
            rB1[j] = *(const uint4*)(gBl + j * 8);
        }

        for (int kc = 0; kc < HID / 64; ++kc) {
            __syncthreads();
            #pragma unroll
            for (int j = 0; j < 4; ++j) {
                *(uint4*)&Ah[srow * 72 + skq * 32 + j * 8] = rA0[j];
                *(uint4*)&Al[srow * 72 + skq * 32 + j * 8] = rA1[j];
                *(uint4*)&Bh[srow * 72 + skq * 32 + j * 8] = rB0[j];
                *(uint4*)&Bl[srow * 72 + skq * 32 + j * 8] = rB1[j];
            }
            __syncthreads();
            if (kc + 1 < HID / 64) {
                const int kt = (kc + 1) * 64;
                #pragma unroll
                for (int j = 0; j < 4; ++j) {
                    rA0[j] = *(const uint4*)(gAh + kt + j * 8);
                    rA1[j] = *(const uint4*)(gAl + kt + j * 8);
                    rB0[j] = *(const uint4*)(gBh + kt + j * 8);
                    rB1[j] = *(const uint4*)(gBl + kt + j * 8);
                }
            }
            const int g = lane >> 4;
            #pragma unroll
            for (int s = 0; s < 2; ++s) {
                bf16x8 fah[4], fal[4], fbh[4], fbl[4];
                #pragma unroll
                for (int mi = 0; mi < 4; ++mi) {
                    int o = (wm * 64 + mi * 16 + (lane & 15)) * 72 + s * 32 + g * 8;
                    fah[mi] = *(const bf16x8*)&Ah[o];
                    fal[mi] = *(const bf16x8*)&Al[o];
                }
                #pragma unroll
                for (int ni = 0; ni < 4; ++ni) {
                    int o = (wn * 64 + ni * 16 + (lane & 15)) * 72 + s * 32 + g * 8;
                    fbh[ni] = *(const bf16x8*)&Bh[o];
                    fbl[ni] = *(const bf16x8*)&Bl[o];
                }
                #pragma unroll
                for (int mi = 0; mi < 4; ++mi)
                    #pragma unroll
                    for (int ni = 0; ni < 4; ++ni) {
                        acc[mi][ni] = __builtin_amdgcn_mfma_f32_16x16x32_bf16(fah[mi], fbh[ni], acc[mi][ni], 0, 0, 0);
                        acc[mi][ni] = __builtin_amdgcn_mfma_f32_16x16x32_bf16(fah[mi], fbl[ni], acc[mi][ni], 0, 0, 0);
                        acc[mi][ni] = __builtin_amdgcn_mfma_f32_16x16x32_bf16(fal[mi], fbh[ni], acc[mi][ni], 0, 0, 0);
                    }
            }
        }

        // epilogue: LDS transpose -> coalesced float4 RMW
        __syncthreads();
        float* Cs = (float*)smem;   // [128][132]
        const int r4 = (lane >> 4) * 4;
        #pragma unroll
        for (int mi = 0; mi < 4; ++mi)
            #pragma unroll
            for (int ni = 0; ni < 4; ++ni) {
                const int col = wn * 64 + ni * 16 + (lane & 15);
                const int row = wm * 64 + mi * 16 + r4;
                #pragma unroll
                for (int r = 0; r < 4; ++r)
                    Cs[(row + r) * 132 + col] = acc[mi][ni][r];
            }
        __syncthreads();
        #pragma unroll
        for (int i = 0; i < 16; ++i) {
            int row = i * 8 + (tid >> 5);
            if (bm * 128 + row < n) {
                int t = s_node[row];
                float* dst = Hbuf + (size_t)t * R5 + HID + bn * 128 + (tid & 31) * 4;
                float4 o = *(const float4*)dst;
                const float* cp = &Cs[row * 132 + (tid & 31) * 4];
                o.x += cp[0]; o.y += cp[1]; o.z += cp[2]; o.w += cp[3];
                *(float4*)dst = o;
            }
        }
    }
}

// ---------------------------------------------------------------------------
// Kernel 5 (per level): fused gates + cell update + output dist + argmax.
// Block handles 32 nodes: phase 1 = elementwise gates (8 threads/node),
// phase 2 = dist MFMA from hh/hl (L2-hot) + argmax + commitment.
// ---------------------------------------------------------------------------
__global__ __launch_bounds__(256, 2)
void gates_dist(int lvl,
                const int* __restrict__ level_start,
                const int* __restrict__ level_nodes,
                const int* __restrict__ proc_order,
                const int* __restrict__ parent_pos,
                const float* __restrict__ Hbuf,
                const float* __restrict__ Xemb,
                const ushort* __restrict__ Woh, const ushort* __restrict__ Wol,
                const float* __restrict__ b_out,
                const ushort* __restrict__ zpad,
                ushort* __restrict__ hh, ushort* __restrict__ hl,
                float* __restrict__ c_all,
                int* __restrict__ eidx_all,
                float* __restrict__ out)
{
    const int s0 = level_start[lvl];
    const int n  = level_start[lvl + 1] - s0;
    const int bm = blockIdx.x;
    if (bm * 32 >= n) return;
    const int tid = threadIdx.x;
    const int lane = tid & 63;
    const int wid = tid >> 6;
    const int wm = wid & 1, wn = wid >> 1;

    __shared__ __align__(16) ushort smem[384 * 72];   // 55296 B
    ushort* Ah = smem;              // 32*72
    ushort* Al = smem + 32 * 72;
    ushort* Bh = smem + 64 * 72;    // 160*72
    ushort* Bl = smem + 224 * 72;
    __shared__ int s_node[32];

    if (tid < 32) {
        int m = bm * 32 + tid;
        s_node[tid] = (m < n) ? level_nodes[s0 + m] : -1;
    }
    __syncthreads();

    // ---- phase 1: gates (8 threads per node, 128 elems each) ----
    const int m = tid >> 3, sub = tid & 7;
    const int t = s_node[m];
    if (t >= 0) {
        const int pid = parent_pos[t];
        const int eidx = (pid < 0) ? 0 : eidx_all[pid];
        const float4* H4 = (const float4*)(Hbuf + (size_t)t * R5);
        const float4* E4 = (const float4*)(Xemb + (size_t)eidx * R5);
        const float4* PC4 = (pid < 0) ? nullptr : (const float4*)(c_all + (size_t)pid * HID);
        float4* C4 = (float4*)(c_all + (size_t)t * HID);
        ushort* hhp = hh + (size_t)t * HID;
        ushort* hlp = hl + (size_t)t * HID;
        for (int i = 0; i < 32; ++i) {
            const int j = i * 8 + sub;   // float4 index 0..255
            float4 Hpx = H4[j],        Epx = E4[j];
            float4 Hi  = H4[256 + j],  Ei  = E4[256 + j];
            float4 Ho  = H4[512 + j],  Eo  = E4[512 + j];
            float4 Hu  = H4[768 + j],  Eu  = E4[768 + j];
            float4 Hf  = H4[1024 + j], Ef  = E4[1024 + j];
            float4 PC = PC4 ? PC4[j] : make_float4(0.f, 0.f, 0.f, 0.f);

            float cv[4], hv[4];
#define GATE(CP, IDX) { \
            float pxv = Hpx.CP + Epx.CP; \
            float iv  = Hi.CP + Ei.CP; \
            float ov  = Ho.CP + Eo.CP; \
            float uv  = Hu.CP + Eu.CP; \
            float fv  = Hf.CP + Ef.CP; \
            float ig = sigf(iv), og = sigf(ov), ug = tanhf(uv), fg = sigf(fv); \
            float cc = ig * ug + fg * PC.CP; \
            cv[IDX] = cc; \
            hv[IDX] = og * tanhf(cc) * sigf(pxv); }
            GATE(x, 0) GATE(y, 1) GATE(z, 2) GATE(w, 3)
#undef GATE

            C4[j] = make_float4(cv[0], cv[1], cv[2], cv[3]);
            ushort4 shi, slo;
            split2(hv[0], shi.x, slo.x); split2(hv[1], shi.y, slo.y);
            split2(hv[2], shi.z, slo.z); split2(hv[3], shi.w, slo.w);
            *(ushort4*)(hhp + j * 4) = shi;
            *(ushort4*)(hlp + j * 4) = slo;
        }
    }
    __syncthreads();   // drains vmcnt; hh/hl visible via L2 (L1 invalidated on write)

    // ---- phase 2: dist = W_out @ h (split-bf16 MFMA), argmax, commitment ----
    const int arow = tid >> 3, apc = (tid & 7) * 8;
    const int ta = s_node[arow];
    const ushort* gAh = (ta >= 0 ? hh + (size_t)ta * HID : zpad) + apc;
    const ushort* gAl = (ta >= 0 ? hl + (size_t)ta * HID : zpad) + apc;

    f32x4 acc[5];
    #pragma unroll
    for (int f = 0; f < 5; ++f) acc[f] = (f32x4){0.f, 0.f, 0.f, 0.f};

    uint4 rA0, rA1, rB0[5], rB1[5];
    rA0 = *(const uint4*)gAh;
    rA1 = *(const uint4*)gAl;
    #pragma unroll
    for (int j = 0; j < 5; ++j) {
        int i = tid + j * 256;
        int brow = i >> 3, bpc = (i & 7) * 8;
        rB0[j] = *(const uint4*)(Woh + (size_t)brow * HID + bpc);
        rB1[j] = *(const uint4*)(Wol + (size_t)brow * HID + bpc);
    }

    for (int kc = 0; kc < HID / 64; ++kc) {
        __syncthreads();
        *(uint4*)&Ah[arow * 72 + apc] = rA0;
        *(uint4*)&Al[arow * 72 + apc] = rA1;
        #pragma unroll
        for (int j = 0; j < 5; ++j) {
            int i = tid + j * 256;
            int brow = i >> 3, bpc = (i & 7) * 8;
            *(uint4*)&Bh[brow * 72 + bpc] = rB0[j];
            *(uint4*)&Bl[brow * 72 + bpc] = rB1[j];
        }
        __syncthreads();
        if (kc + 1 < HID / 64) {
            const int kt = (kc + 1) * 64;
            rA0 = *(const uint4*)(gAh + kt);
            rA1 = *(const uint4*)(gAl + kt);
            #pragma unroll
            for (int j = 0; j < 5; ++j) {
                int i = tid + j * 256;
                int brow = i >> 3, bpc = (i & 7) * 8;
                rB0[j] = *(const uint4*)(Woh + (size_t)brow * HID + kt + bpc);
                rB1[j] = *(const uint4*)(Wol + (size_t)brow * HID + kt + bpc);
            }
        }
        const int g = lane >> 4;
        #pragma unroll
        for (int s = 0; s < 2; ++s) {
            int ao = (wm * 16 + (lane & 15)) * 72 + s * 32 + g * 8;
            bf16x8 fah = *(const bf16x8*)&Ah[ao];
            bf16x8 fal = *(const bf16x8*)&Al[ao];
            #pragma unroll
            for (int f = 0; f < 5; ++f) {
                int bo = (wn * 80 + f * 16 + (lane & 15)) * 72 + s * 32 + g * 8;
                bf16x8 fbh = *(const bf16x8*)&Bh[bo];
                bf16x8 fbl = *(const bf16x8*)&Bl[bo];
                acc[f] = __builtin_amdgcn_mfma_f32_16x16x32_bf16(fah, fbh, acc[f], 0, 0, 0);
                acc[f] = __builtin_amdgcn_mfma_f32_16x16x32_bf16(fah, fbl, acc[f], 0, 0, 0);
                acc[f] = __builtin_amdgcn_mfma_f32_16x16x32_bf16(fal, fbh, acc[f], 0, 0, 0);
            }
        }
    }

    __syncthreads();
    float* ds = (float*)smem;   // [32][172] = 22016 B
    const int r4 = (lane >> 4) * 4;
    #pragma unroll
    for (int f = 0; f < 5; ++f) {
        const int col = wn * 80 + f * 16 + (lane & 15);
        const int row = wm * 16 + r4;
        #pragma unroll
        for (int r = 0; r < 4; ++r)
            ds[(row + r) * 172 + col] = acc[f][r];
    }
    __syncthreads();

    float bv = -3.4e38f; int bc = NCLS;
    if (bm * 32 + m < n) {
        const int tt = s_node[m];
        const int node = proc_order[tt];
        float* drow = out + (size_t)node * NCLS;
        for (int c = sub; c < NCLS; c += 8) {
            float v = ds[m * 172 + c] + b_out[c];
            drow[c] = v;
            if (c >= 1 && (v > bv || (v == bv && c < bc))) { bv = v; bc = c; }
        }
        #pragma unroll
        for (int off = 4; off > 0; off >>= 1) {
            float ov = __shfl_down(bv, off, 64);
            int   oc = __shfl_down(bc, off, 64);
            if (ov > bv || (ov == bv && oc < bc)) { bv = ov; bc = oc; }
        }
        if (sub == 0) {
            eidx_all[tt] = bc + 1;
            out[(size_t)N_OBJ * NCLS + node] = (float)bc;
        }
    }
}

// ---------------------------------------------------------------------------
extern "C" void kernel_launch(void* const* d_in, const int* in_sizes, int n_in,
                              void* d_out, int out_size, void* d_ws, size_t ws_size,
                              hipStream_t stream)
{
    const float* features = (const float*)d_in[0];
    const float* embed_W  = (const float*)d_in[1];
    const float* W_px     = (const float*)d_in[2];
    const float* b_px     = (const float*)d_in[3];
    const float* W_ioux   = (const float*)d_in[4];
    const float* b_ioux   = (const float*)d_in[5];
    const float* W_iouh   = (const float*)d_in[6];
    const float* b_iouh   = (const float*)d_in[7];
    const float* W_fx     = (const float*)d_in[8];
    const float* b_fx     = (const float*)d_in[9];
    const float* W_fh     = (const float*)d_in[10];
    const float* b_fh     = (const float*)d_in[11];
    const float* W_out    = (const float*)d_in[12];
    const float* b_out    = (const float*)d_in[13];
    const int* proc_order = (const int*)d_in[14];
    const int* parent_pos = (const int*)d_in[15];
    float* out = (float*)d_out;

    // workspace layout (~176 MB)
    float* Hbuf  = (float*)d_ws;                          // [N_OBJ][R5]
    float* c_all = Hbuf + (size_t)N_OBJ * R5;             // [N_OBJ][HID]
    float* Xemb  = c_all + (size_t)N_OBJ * HID;           // [NEMB][R5]
    ushort* Whh = (ushort*)(Xemb + (size_t)NEMB * R5);    // [RH][HID]
    ushort* Whl = Whh + (size_t)RH * HID;
    ushort* Wxh = Whl + (size_t)RH * HID;                 // [R5][IN_DIM]
    ushort* Wxl = Wxh + (size_t)R5 * IN_DIM;
    ushort* Fh  = Wxl + (size_t)R5 * IN_DIM;              // [N_OBJ][IN_DIM]
    ushort* Fl  = Fh + (size_t)N_OBJ * IN_DIM;
    ushort* hh  = Fl + (size_t)N_OBJ * IN_DIM;            // [N_OBJ][HID]
    ushort* hl  = hh + (size_t)N_OBJ * HID;
    ushort* Woh = hl + (size_t)N_OBJ * HID;               // [NCPAD][HID]
    ushort* Wol = Woh + (size_t)NCPAD * HID;
    ushort* zpad = Wol + (size_t)NCPAD * HID;             // [1024] zeros
    int* eidx_all    = (int*)(zpad + 1024);
    int* level_nodes = eidx_all + N_OBJ;
    int* level_start = level_nodes + N_OBJ;

    build_levels<<<1, 1024, 0, stream>>>(parent_pos, level_nodes, level_start, zpad);
    xemb_kernel<<<dim3(NEMB, R5 / 256), 256, 0, stream>>>(
        embed_W, W_px, W_ioux, W_fx, b_px, b_ioux, b_iouh, b_fx, b_fh, Xemb);
    convert_wh<<<RH * HID / 1024, 256, 0, stream>>>(W_iouh, W_fh, Whh, Whl);
    convert_wx<<<R5 * IN_DIM / 1024, 256, 0, stream>>>(W_px, W_ioux, W_fx, Wxh, Wxl);
    convert_f<<<N_OBJ * IN_DIM / 1024, 256, 0, stream>>>(features, proc_order, Fh, Fl);
    convert_wout<<<NCPAD * HID / 1024, 256, 0, stream>>>(W_out, Woh, Wol);

    xgemm_mfma<<<(N_OBJ / 128) * (R5 / 128), 256, 0, stream>>>(Fh, Fl, Wxh, Wxl, Hbuf);

    gates_dist<<<N_OBJ / 32, 256, 0, stream>>>(
        0, level_start, level_nodes, proc_order, parent_pos,
        Hbuf, Xemb, Woh, Wol, b_out, zpad, hh, hl, c_all, eidx_all, out);

    for (int l = 1; l < MAXLVL; ++l) {
        hgemm_mfma<<<dim3(8, RH / 128), 256, 0, stream>>>(
            l, level_start, level_nodes, parent_pos, hh, hl, Whh, Whl, zpad, Hbuf);
        gates_dist<<<N_OBJ / 32, 256, 0, stream>>>(
            l, level_start, level_nodes, proc_order, parent_pos,
            Hbuf, Xemb, Woh, Wol, b_out, zpad, hh, hl, c_all, eidx_all, out);
    }
}

// Round 7
// 2888.769 us; speedup vs baseline: 1.4215x; 1.4215x over previous
//
#include <hip/hip_runtime.h>
#include <hip/hip_bf16.h>
#include <hip/hip_cooperative_groups.h>
#include <math.h>

namespace cg = cooperative_groups;

#define N_OBJ 4096
#define IN_DIM 1024
#define EMB_D 200
#define HID 1024
#define NCLS 151
#define IN_SZ 1224      // IN_DIM + EMB_D
#define NEMB 152        // NCLS + 1 embedding rows
#define R5 5120         // px(1024) + iou(3072) + f(1024) pre-activation rows
#define RH 4096         // h-dependent rows (iou 3072 + f 1024)
#define MAXLVL 32

typedef __attribute__((ext_vector_type(8))) short bf16x8;
typedef __attribute__((ext_vector_type(4))) float f32x4;

__device__ __forceinline__ float sigf(float x) { return 1.f / (1.f + expf(-x)); }

// split fp32 into hi+lo bf16 (RNE both stages); hi+lo carries ~18 mantissa bits
__device__ __forceinline__ void split2(float x, ushort& hi, ushort& lo) {
    unsigned u = __float_as_uint(x);
    unsigned r = u + 0x7FFFu + ((u >> 16) & 1u);
    hi = (ushort)(r >> 16);
    float rem = x - __uint_as_float(r & 0xFFFF0000u);
    unsigned u2 = __float_as_uint(rem);
    unsigned r2 = u2 + 0x7FFFu + ((u2 >> 16) & 1u);
    lo = (ushort)(r2 >> 16);
}

// async global->LDS, 16B per lane; LDS dest must be wave-uniform base (+lane*16)
__device__ __forceinline__ void gload16(const ushort* src, ushort* dst) {
    __builtin_amdgcn_global_load_lds(
        (const __attribute__((address_space(1))) void*)src,
        (__attribute__((address_space(3))) void*)dst, 16, 0, 0);
}

// ---------------------------------------------------------------------------
// Kernel 1: depth per step, bucket steps by level; also zero zpad.
// ---------------------------------------------------------------------------
__global__ __launch_bounds__(1024)
void build_levels(const int* __restrict__ parent_pos,
                  int* __restrict__ level_nodes,
                  int* __restrict__ level_start,
                  ushort* __restrict__ zpad)
{
    __shared__ int dep[N_OBJ];
    __shared__ int par[N_OBJ];
    __shared__ int cnt[MAXLVL];
    __shared__ int offs[MAXLVL];
    __shared__ int base[MAXLVL + 1];
    __shared__ int done;
    const int tid = threadIdx.x;

    if (tid < 1024) zpad[tid] = 0;

    for (int t = tid; t < N_OBJ; t += 1024) {
        int p = parent_pos[t];
        par[t] = p;
        dep[t] = (p < 0) ? 0 : -1;
    }
    for (int l = tid; l < MAXLVL; l += 1024) { cnt[l] = 0; offs[l] = 0; }
    __syncthreads();

    for (int it = 0; it < 64; ++it) {
        if (tid == 0) done = 1;
        __syncthreads();
        for (int t = tid; t < N_OBJ; t += 1024) {
            if (dep[t] < 0) {
                int dp = dep[par[t]];
                if (dp >= 0) dep[t] = dp + 1;
                else done = 0;
            }
        }
        __syncthreads();
        int d = done;
        __syncthreads();
        if (d) break;
    }

    for (int t = tid; t < N_OBJ; t += 1024) {
        int d = dep[t];
        if (d < 0 || d >= MAXLVL) d = MAXLVL - 1;  // safety clamp
        dep[t] = d;
        atomicAdd(&cnt[d], 1);
    }
    __syncthreads();
    if (tid == 0) {
        base[0] = 0;
        for (int l = 0; l < MAXLVL; ++l) base[l + 1] = base[l] + cnt[l];
    }
    __syncthreads();
    for (int t = tid; t < N_OBJ; t += 1024) {
        int d = dep[t];
        int pos = base[d] + atomicAdd(&offs[d], 1);
        level_nodes[pos] = t;
    }
    for (int l = tid; l <= MAXLVL; l += 1024) level_start[l] = base[l];
}

// ---------------------------------------------------------------------------
// Kernel 2: Xemb[e][r] = W_row_r[:, 1024:1224] @ embed_W[e] + (all biases)
// ---------------------------------------------------------------------------
__global__ __launch_bounds__(256)
void xemb_kernel(const float* __restrict__ embed_W,
                 const float* __restrict__ W_px,
                 const float* __restrict__ W_ioux,
                 const float* __restrict__ W_fx,
                 const float* __restrict__ b_px,
                 const float* __restrict__ b_ioux,
                 const float* __restrict__ b_iouh,
                 const float* __restrict__ b_fx,
                 const float* __restrict__ b_fh,
                 float* __restrict__ Xemb)
{
    __shared__ float e_s[EMB_D];
    const int e = blockIdx.x;
    const int r = blockIdx.y * 256 + threadIdx.x;
    for (int k = threadIdx.x; k < EMB_D; k += 256) e_s[k] = embed_W[(size_t)e * EMB_D + k];
    __syncthreads();

    const float* wrow;
    float bias;
    if (r < HID) {
        wrow = W_px + (size_t)r * IN_SZ;
        bias = b_px[r];
    } else if (r < 4 * HID) {
        wrow = W_ioux + (size_t)(r - HID) * IN_SZ;
        bias = b_ioux[r - HID] + b_iouh[r - HID];
    } else {
        wrow = W_fx + (size_t)(r - 4 * HID) * IN_SZ;
        bias = b_fx[r - 4 * HID] + b_fh[r - 4 * HID];
    }

    float s = bias;
    for (int k = 0; k < EMB_D; ++k) s += wrow[IN_DIM + k] * e_s[k];
    Xemb[(size_t)e * R5 + r] = s;
}

// ---------------------------------------------------------------------------
// One-time split-conversion kernels (fp32 -> hi/lo bf16 pairs)
// ---------------------------------------------------------------------------
__global__ __launch_bounds__(256)
void convert_wh(const float* __restrict__ W_iouh, const float* __restrict__ W_fh,
                ushort* __restrict__ Whh, ushort* __restrict__ Whl)
{
    const int idx = (blockIdx.x * 256 + threadIdx.x) * 4;
    const int row = idx >> 10, k = idx & 1023;
    const float* src = (row < 3 * HID) ? (W_iouh + (size_t)row * HID + k)
                                       : (W_fh + (size_t)(row - 3 * HID) * HID + k);
    float4 v = *(const float4*)src;
    ushort4 hi, lo;
    split2(v.x, hi.x, lo.x); split2(v.y, hi.y, lo.y);
    split2(v.z, hi.z, lo.z); split2(v.w, hi.w, lo.w);
    *(ushort4*)(Whh + (size_t)row * HID + k) = hi;
    *(ushort4*)(Whl + (size_t)row * HID + k) = lo;
}

__global__ __launch_bounds__(256)
void convert_wx(const float* __restrict__ W_px, const float* __restrict__ W_ioux,
                const float* __restrict__ W_fx,
                ushort* __restrict__ Wxh, ushort* __restrict__ Wxl)
{
    const int idx = (blockIdx.x * 256 + threadIdx.x) * 4;
    const int row = idx >> 10, k = idx & 1023;
    const float* src;
    if (row < HID)          src = W_px   + (size_t)row * IN_SZ + k;
    else if (row < 4 * HID) src = W_ioux + (size_t)(row - HID) * IN_SZ + k;
    else                    src = W_fx   + (size_t)(row - 4 * HID) * IN_SZ + k;
    float4 v = *(const float4*)src;
    ushort4 hi, lo;
    split2(v.x, hi.x, lo.x); split2(v.y, hi.y, lo.y);
    split2(v.z, hi.z, lo.z); split2(v.w, hi.w, lo.w);
    *(ushort4*)(Wxh + (size_t)row * IN_DIM + k) = hi;
    *(ushort4*)(Wxl + (size_t)row * IN_DIM + k) = lo;
}

__global__ __launch_bounds__(256)
void convert_f(const float* __restrict__ features, const int* __restrict__ proc_order,
               ushort* __restrict__ Fh, ushort* __restrict__ Fl)
{
    const int idx = (blockIdx.x * 256 + threadIdx.x) * 4;
    const int t = idx >> 10, k = idx & 1023;
    const float* src = features + (size_t)proc_order[t] * IN_DIM + k;
    float4 v = *(const float4*)src;
    ushort4 hi, lo;
    split2(v.x, hi.x, lo.x); split2(v.y, hi.y, lo.y);
    split2(v.z, hi.z, lo.z); split2(v.w, hi.w, lo.w);
    *(ushort4*)(Fh + (size_t)t * IN_DIM + k) = hi;
    *(ushort4*)(Fl + (size_t)t * IN_DIM + k) = lo;
}

// ---------------------------------------------------------------------------
// Kernel 3 (ONCE): x-part GEMM via split-bf16 MFMA.
// global_load_lds staging (no staging VGPRs -> no spills), double-buffered
// BK=32, XOR-swizzled source + swizzled ds_read (2-way, free).
// ---------------------------------------------------------------------------
__global__ __launch_bounds__(256, 2)
void xgemm_mfma(const ushort* __restrict__ Fh, const ushort* __restrict__ Fl,
                const ushort* __restrict__ Wxh, const ushort* __restrict__ Wxl,
                float* __restrict__ Hbuf)
{
    const int bid = blockIdx.x;
    const int sup = bid >> 6, within = bid & 63;
    const int bm = (sup & 3) * 8 + (within & 7);
    const int bn = (sup >> 2) * 8 + (within >> 3);

    // 2 bufs x 4 matrices x 128 rows x 32 shorts = 65536 B
    __shared__ __align__(16) ushort smem[2][4][128 * 32];

    const int tid = threadIdx.x;
    const int lane = tid & 63;
    const int wid = tid >> 6;
    const int wm = wid & 1, wn = wid >> 1;
    const int g = lane >> 4;
    const int lr = lane >> 2, cg4 = lane & 3;

    const ushort* gsrc =
        (wid == 0) ? Fh  + (size_t)(bm * 128) * IN_DIM :
        (wid == 1) ? Fl  + (size_t)(bm * 128) * IN_DIM :
        (wid == 2) ? Wxh + (size_t)(bn * 128) * IN_DIM :
                     Wxl + (size_t)(bn * 128) * IN_DIM;

    f32x4 acc[4][4];
    #pragma unroll
    for (int i = 0; i < 4; ++i)
        #pragma unroll
        for (int j = 0; j < 4; ++j)
            acc[i][j] = (f32x4){0.f, 0.f, 0.f, 0.f};

    // prologue: stage chunk 0 into buf 0 (wave wid handles matrix wid)
    #pragma unroll
    for (int i = 0; i < 8; ++i) {
        int row = i * 16 + lr;
        int cs = (cg4 ^ ((row >> 1) & 3)) << 3;
        gload16(gsrc + (size_t)row * IN_DIM + cs, &smem[0][wid][i * 512]);
    }
    __syncthreads();

    int cur = 0;
    for (int kc = 0; kc < IN_DIM / 32; ++kc) {
        if (kc + 1 < IN_DIM / 32) {
            const int kt = (kc + 1) * 32;
            #pragma unroll
            for (int i = 0; i < 8; ++i) {
                int row = i * 16 + lr;
                int cs = (cg4 ^ ((row >> 1) & 3)) << 3;
                gload16(gsrc + (size_t)row * IN_DIM + kt + cs, &smem[cur ^ 1][wid][i * 512]);
            }
        }
        const ushort* Ahb = &smem[cur][0][0];
        const ushort* Alb = &smem[cur][1][0];
        const ushort* Bhb = &smem[cur][2][0];
        const ushort* Blb = &smem[cur][3][0];
        bf16x8 fa[8];
        #pragma unroll
        for (int mi = 0; mi < 4; ++mi) {
            int row = wm * 64 + mi * 16 + (lane & 15);
            int off = row * 32 + ((g ^ ((row >> 1) & 3)) << 3);
            fa[2 * mi]     = *(const bf16x8*)&Ahb[off];
            fa[2 * mi + 1] = *(const bf16x8*)&Alb[off];
        }
        #pragma unroll
        for (int ni = 0; ni < 4; ++ni) {
            int row = wn * 64 + ni * 16 + (lane & 15);
            int off = row * 32 + ((g ^ ((row >> 1) & 3)) << 3);
            bf16x8 fbh = *(const bf16x8*)&Bhb[off];
            bf16x8 fbl = *(const bf16x8*)&Blb[off];
            #pragma unroll
            for (int mi = 0; mi < 4; ++mi) {
                acc[mi][ni] = __builtin_amdgcn_mfma_f32_16x16x32_bf16(fa[2*mi],   fbh, acc[mi][ni], 0, 0, 0);
                acc[mi][ni] = __builtin_amdgcn_mfma_f32_16x16x32_bf16(fa[2*mi],   fbl, acc[mi][ni], 0, 0, 0);
                acc[mi][ni] = __builtin_amdgcn_mfma_f32_16x16x32_bf16(fa[2*mi+1], fbh, acc[mi][ni], 0, 0, 0);
            }
        }
        __syncthreads();   // drains vmcnt(0): next buffer ready, this buffer's reads done
        cur ^= 1;
    }

    // epilogue: LDS transpose (two 64-row passes) -> coalesced float4 writes
    float* Cs = (float*)&smem[0][0][0];   // [64][132] = 33792 B
    const int t0 = bm * 128, c0 = bn * 128;
    const int r4 = (lane >> 4) * 4;
    #pragma unroll
    for (int p = 0; p < 2; ++p) {
        if (wm == p) {
            #pragma unroll
            for (int mi = 0; mi < 4; ++mi)
                #pragma unroll
                for (int ni = 0; ni < 4; ++ni) {
                    int row = mi * 16 + r4;
                    int col = wn * 64 + ni * 16 + (lane & 15);
                    #pragma unroll
                    for (int r = 0; r < 4; ++r)
                        Cs[(row + r) * 132 + col] = acc[mi][ni][r];
                }
        }
        __syncthreads();
        #pragma unroll
        for (int i = 0; i < 8; ++i) {
            int row = i * 8 + (tid >> 5);
            float4 v = *(const float4*)&Cs[row * 132 + (tid & 31) * 4];
            *(float4*)&Hbuf[(size_t)(t0 + p * 64 + row) * R5 + c0 + (tid & 31) * 4] = v;
        }
        __syncthreads();
    }
}

// ---------------------------------------------------------------------------
// hgemm tile body: 64 nodes x 128 weight-rows, K=1024, split-bf16 MFMA,
// global_load_lds staging (A gathered per-lane by parent), BK=32 dbuf.
// csm must be >= 24576 ushorts (49152 B).
// ---------------------------------------------------------------------------
__device__ __forceinline__ void hgemm_tile(
    int s0, int n, int bm, int bn,
    const int* __restrict__ level_nodes, const int* __restrict__ parent_pos,
    const ushort* __restrict__ hh, const ushort* __restrict__ hl,
    const ushort* __restrict__ Whh, const ushort* __restrict__ Whl,
    const ushort* __restrict__ zpad, float* __restrict__ Hbuf,
    ushort* csm, int* s_node, int* s_par)
{
    const int tid = threadIdx.x;
    const int lane = tid & 63;
    const int wid = tid >> 6;
    const int wm = wid & 1, wn = wid >> 1;
    const int g = lane >> 4;
    const int lr = lane >> 2, cg4 = lane & 3;

    __syncthreads();   // protect smem reuse from previous tile/phase
    if (tid < 64) {
        int m = bm * 64 + tid;
        if (m < n) {
            int t = level_nodes[s0 + m];
            s_node[tid] = t;
            s_par[tid]  = parent_pos[t];
        } else { s_node[tid] = -1; s_par[tid] = -1; }
    }
    __syncthreads();

    f32x4 acc[2][4];
    #pragma unroll
    for (int i = 0; i < 2; ++i)
        #pragma unroll
        for (int j = 0; j < 4; ++j)
            acc[i][j] = (f32x4){0.f, 0.f, 0.f, 0.f};

    // buffer layout per buf (12288 shorts): [Ah 2048][Al 2048][Bh 4096][Bl 4096]
    auto stage = [&](int buf, int kt) {
        ushort* base = csm + buf * 12288;
        if (wid < 2) {
            const ushort* hsrc = (wid == 0) ? hh : hl;
            ushort* ld = base + wid * 2048;
            #pragma unroll
            for (int i = 0; i < 4; ++i) {
                int row = i * 16 + lr;
                int cs = (cg4 ^ ((row >> 1) & 3)) << 3;
                int par = s_par[row];
                const ushort* sp = (par >= 0) ? (hsrc + (size_t)par * HID + kt + cs)
                                              : (zpad + cs);
                gload16(sp, ld + i * 512);
            }
        } else {
            const ushort* wsrc = (wid == 2) ? Whh : Whl;
            ushort* ld = base + 4096 + (wid - 2) * 4096;
            #pragma unroll
            for (int i = 0; i < 8; ++i) {
                int row = i * 16 + lr;
                int cs = (cg4 ^ ((row >> 1) & 3)) << 3;
                gload16(wsrc + (size_t)(bn * 128 + row) * HID + kt + cs, ld + i * 512);
            }
        }
    };

    stage(0, 0);
    __syncthreads();
    int cur = 0;
    for (int kc = 0; kc < HID / 32; ++kc) {
        if (kc + 1 < HID / 32) stage(cur ^ 1, (kc + 1) * 32);
        const ushort* base = csm + cur * 12288;
        const ushort* Ahb = base;
        const ushort* Alb = base + 2048;
        const ushort* Bhb = base + 4096;
        const ushort* Blb = base + 8192;
        bf16x8 fa[4];
        #pragma unroll
        for (int mi = 0; mi < 2; ++mi) {
            int row = wm * 32 + mi * 16 + (lane & 15);
            int off = row * 32 + ((g ^ ((row >> 1) & 3)) << 3);
            fa[2 * mi]     = *(const bf16x8*)&Ahb[off];
            fa[2 * mi + 1] = *(const bf16x8*)&Alb[off];
        }
        #pragma unroll
        for (int ni = 0; ni < 4; ++ni) {
            int row = wn * 64 + ni * 16 + (lane & 15);
            int off = row * 32 + ((g ^ ((row >> 1) & 3)) << 3);
            bf16x8 fbh = *(const bf16x8*)&Bhb[off];
            bf16x8 fbl = *(const bf16x8*)&Blb[off];
            #pragma unroll
            for (int mi = 0; mi < 2; ++mi) {
                acc[mi][ni] = __builtin_amdgcn_mfma_f32_16x16x32_bf16(fa[2*mi],   fbh, acc[mi][ni], 0, 0, 0);
                acc[mi][ni] = __builtin_amdgcn_mfma_f32_16x16x32_bf16(fa[2*mi],   fbl, acc[mi][ni], 0, 0, 0);
                acc[mi][ni] = __builtin_amdgcn_mfma_f32_16x16x32_bf16(fa[2*mi+1], fbh, acc[mi][ni], 0, 0, 0);
            }
        }
        __syncthreads();
        cur ^= 1;
    }

    // epilogue: LDS transpose -> coalesced float4 RMW
    float* Cs = (float*)csm;   // [64][132] = 33792 B
    const int r4 = (lane >> 4) * 4;
    #pragma unroll
    for (int mi = 0; mi < 2; ++mi)
        #pragma unroll
        for (int ni = 0; ni < 4; ++ni) {
            int row = wm * 32 + mi * 16 + r4;
            int col = wn * 64 + ni * 16 + (lane & 15);
            #pragma unroll
            for (int r = 0; r < 4; ++r)
                Cs[(row + r) * 132 + col] = acc[mi][ni][r];
        }
    __syncthreads();
    #pragma unroll
    for (int i = 0; i < 8; ++i) {
        int row = i * 8 + (tid >> 5);
        if (bm * 64 + row < n) {
            int t = s_node[row];
            float* dst = Hbuf + (size_t)t * R5 + HID + bn * 128 + (tid & 31) * 4;
            float4 o = *(const float4*)dst;
            const float* cp = &Cs[row * 132 + (tid & 31) * 4];
            o.x += cp[0]; o.y += cp[1]; o.z += cp[2]; o.w += cp[3];
            *(float4*)dst = o;
        }
    }
}

// ---------------------------------------------------------------------------
// gates + dist body for one node (256 threads). hs = 1024 floats of LDS.
// ---------------------------------------------------------------------------
__device__ __forceinline__ void gates_dist_node(
    int t,
    const int* __restrict__ proc_order, const int* __restrict__ parent_pos,
    const float* __restrict__ Hbuf, const float* __restrict__ Xemb,
    const float* __restrict__ W_out, const float* __restrict__ b_out,
    ushort* __restrict__ hh, ushort* __restrict__ hl,
    float* __restrict__ c_all, int* __restrict__ eidx_all, float* __restrict__ out,
    float* hs, float* bv_s, int* bi_s)
{
    const int tid = threadIdx.x;
    const int pid = parent_pos[t];
    const int eidx = (pid < 0) ? 0 : eidx_all[pid];

    const float4* H4 = (const float4*)(Hbuf + (size_t)t * R5);
    const float4* E4 = (const float4*)(Xemb + (size_t)eidx * R5);

    float4 Hpx = H4[tid],        Epx = E4[tid];
    float4 Hi  = H4[256 + tid],  Ei  = E4[256 + tid];
    float4 Ho  = H4[512 + tid],  Eo  = E4[512 + tid];
    float4 Hu  = H4[768 + tid],  Eu  = E4[768 + tid];
    float4 Hf  = H4[1024 + tid], Ef  = E4[1024 + tid];
    float4 PC = (pid < 0) ? make_float4(0.f, 0.f, 0.f, 0.f)
                          : ((const float4*)(c_all + (size_t)pid * HID))[tid];

    float cv[4], hv[4];
#define GATE(CP, IDX) { \
    float pxv = Hpx.CP + Epx.CP; \
    float iv  = Hi.CP + Ei.CP; \
    float ov  = Ho.CP + Eo.CP; \
    float uv  = Hu.CP + Eu.CP; \
    float fv  = Hf.CP + Ef.CP; \
    float ig = sigf(iv), og = sigf(ov), ug = tanhf(uv), fg = sigf(fv); \
    float cc = ig * ug + fg * PC.CP; \
    cv[IDX] = cc; \
    hv[IDX] = og * tanhf(cc) * sigf(pxv); }
    GATE(x, 0) GATE(y, 1) GATE(z, 2) GATE(w, 3)
#undef GATE

    float4 c4 = make_float4(cv[0], cv[1], cv[2], cv[3]);
    float4 h4 = make_float4(hv[0], hv[1], hv[2], hv[3]);
    ((float4*)(c_all + (size_t)t * HID))[tid] = c4;
    ((float4*)hs)[tid] = h4;
    ushort4 shi, slo;
    split2(h4.x, shi.x, slo.x); split2(h4.y, shi.y, slo.y);
    split2(h4.z, shi.z, slo.z); split2(h4.w, shi.w, slo.w);
    *(ushort4*)(hh + (size_t)t * HID + (tid << 2)) = shi;
    *(ushort4*)(hl + (size_t)t * HID + (tid << 2)) = slo;
    __syncthreads();

    const int node = proc_order[t];
    float* dists = out + (size_t)node * NCLS;
    const int wave = tid >> 6, lane = tid & 63;

    float bv = -3.4e38f; int bi = NCLS;
    for (int r = wave; r < NCLS; r += 4) {
        const float* wr = W_out + (size_t)r * HID;
        float s = 0.f;
        #pragma unroll
        for (int q = 0; q < 4; ++q) {
            float4 w4 = *(const float4*)(wr + (lane << 2) + q * 256);
            float4 x4 = *(const float4*)(hs + (lane << 2) + q * 256);
            s += w4.x * x4.x + w4.y * x4.y + w4.z * x4.z + w4.w * x4.w;
        }
        #pragma unroll
        for (int off = 32; off > 0; off >>= 1) s += __shfl_down(s, off, 64);
        if (lane == 0) {
            s += b_out[r];
            dists[r] = s;
            if (r >= 1 && s > bv) { bv = s; bi = r; }
        }
    }
    if (lane == 0) { bv_s[wave] = bv; bi_s[wave] = bi; }
    __syncthreads();
    if (tid == 0) {
        float v = bv_s[0]; int b = bi_s[0];
        for (int w = 1; w < 4; ++w)
            if (bv_s[w] > v || (bv_s[w] == v && bi_s[w] < b)) { v = bv_s[w]; b = bi_s[w]; }
        eidx_all[t] = b + 1;
        out[(size_t)N_OBJ * NCLS + node] = (float)b;
    }
    __syncthreads();   // hs / bv_s reused by next node
}

// ---------------------------------------------------------------------------
// Cooperative mega-kernel: whole level loop, grid.sync between phases.
// ---------------------------------------------------------------------------
__global__ __launch_bounds__(256, 2)
void level_loop(const int* __restrict__ level_start, const int* __restrict__ level_nodes,
                const int* __restrict__ proc_order, const int* __restrict__ parent_pos,
                const ushort* __restrict__ Whh, const ushort* __restrict__ Whl,
                const ushort* __restrict__ zpad, const float* __restrict__ Xemb,
                const float* __restrict__ W_out, const float* __restrict__ b_out,
                float* __restrict__ Hbuf, float* __restrict__ c_all,
                ushort* __restrict__ hh, ushort* __restrict__ hl,
                int* __restrict__ eidx_all, float* __restrict__ out)
{
    cg::grid_group grid = cg::this_grid();
    __shared__ __align__(16) ushort csm[24576];   // 49152 B
    __shared__ int s_node[64], s_par[64];
    __shared__ float bv_s[4];
    __shared__ int bi_s[4];

    const int nblk = gridDim.x, bid = blockIdx.x;

    for (int lvl = 0; lvl < MAXLVL; ++lvl) {
        const int s0 = level_start[lvl];
        if (s0 >= N_OBJ) break;
        const int n = level_start[lvl + 1] - s0;
        if (lvl > 0) {
            const int ntile = ((n + 63) >> 6) * 32;
            for (int tile = bid; tile < ntile; tile += nblk)
                hgemm_tile(s0, n, tile >> 5, tile & 31, level_nodes, parent_pos,
                           hh, hl, Whh, Whl, zpad, Hbuf, csm, s_node, s_par);
            grid.sync();
        }
        for (int slot = bid; slot < n; slot += nblk) {
            int t = level_nodes[s0 + slot];
            gates_dist_node(t, proc_order, parent_pos, Hbuf, Xemb, W_out, b_out,
                            hh, hl, c_all, eidx_all, out, (float*)csm, bv_s, bi_s);
        }
        grid.sync();
    }
}

// ---------------------------------------------------------------------------
// Fallback (non-cooperative) per-level kernels using the same bodies.
// ---------------------------------------------------------------------------
__global__ __launch_bounds__(256, 2)
void hgemm_lvl(int lvl, const int* __restrict__ level_start,
               const int* __restrict__ level_nodes, const int* __restrict__ parent_pos,
               const ushort* __restrict__ hh, const ushort* __restrict__ hl,
               const ushort* __restrict__ Whh, const ushort* __restrict__ Whl,
               const ushort* __restrict__ zpad, float* __restrict__ Hbuf)
{
    __shared__ __align__(16) ushort csm[24576];
    __shared__ int s_node[64], s_par[64];
    const int s0 = level_start[lvl];
    const int n  = level_start[lvl + 1] - s0;
    const int bm = blockIdx.y;
    if (bm * 64 >= n) return;
    hgemm_tile(s0, n, bm, blockIdx.x, level_nodes, parent_pos,
               hh, hl, Whh, Whl, zpad, Hbuf, csm, s_node, s_par);
}

__global__ __launch_bounds__(256, 2)
void gates_lvl(int lvl, const int* __restrict__ level_start,
               const int* __restrict__ level_nodes, const int* __restrict__ proc_order,
               const int* __restrict__ parent_pos,
               const float* __restrict__ Hbuf, const float* __restrict__ Xemb,
               const float* __restrict__ W_out, const float* __restrict__ b_out,
               ushort* __restrict__ hh, ushort* __restrict__ hl,
               float* __restrict__ c_all, int* __restrict__ eidx_all,
               float* __restrict__ out)
{
    __shared__ __align__(16) float hs[HID];
    __shared__ float bv_s[4];
    __shared__ int bi_s[4];
    const int s0 = level_start[lvl];
    const int n  = level_start[lvl + 1] - s0;
    for (int slot = blockIdx.x; slot < n; slot += gridDim.x) {
        int t = level_nodes[s0 + slot];
        gates_dist_node(t, proc_order, parent_pos, Hbuf, Xemb, W_out, b_out,
                        hh, hl, c_all, eidx_all, out, hs, bv_s, bi_s);
    }
}

// ---------------------------------------------------------------------------
extern "C" void kernel_launch(void* const* d_in, const int* in_sizes, int n_in,
                              void* d_out, int out_size, void* d_ws, size_t ws_size,
                              hipStream_t stream)
{
    const float* features = (const float*)d_in[0];
    const float* embed_W  = (const float*)d_in[1];
    const float* W_px     = (const float*)d_in[2];
    const float* b_px     = (const float*)d_in[3];
    const float* W_ioux   = (const float*)d_in[4];
    const float* b_ioux   = (const float*)d_in[5];
    const float* W_iouh   = (const float*)d_in[6];
    const float* b_iouh   = (const float*)d_in[7];
    const float* W_fx     = (const float*)d_in[8];
    const float* b_fx     = (const float*)d_in[9];
    const float* W_fh     = (const float*)d_in[10];
    const float* b_fh     = (const float*)d_in[11];
    const float* W_out    = (const float*)d_in[12];
    const float* b_out    = (const float*)d_in[13];
    const int* proc_order = (const int*)d_in[14];
    const int* parent_pos = (const int*)d_in[15];
    float* out = (float*)d_out;

    // workspace layout (~175 MB)
    float* Hbuf  = (float*)d_ws;                          // [N_OBJ][R5]
    float* c_all = Hbuf + (size_t)N_OBJ * R5;             // [N_OBJ][HID]
    float* Xemb  = c_all + (size_t)N_OBJ * HID;           // [NEMB][R5]
    ushort* Whh = (ushort*)(Xemb + (size_t)NEMB * R5);    // [RH][HID]
    ushort* Whl = Whh + (size_t)RH * HID;
    ushort* Wxh = Whl + (size_t)RH * HID;                 // [R5][IN_DIM]
    ushort* Wxl = Wxh + (size_t)R5 * IN_DIM;
    ushort* Fh  = Wxl + (size_t)R5 * IN_DIM;              // [N_OBJ][IN_DIM]
    ushort* Fl  = Fh + (size_t)N_OBJ * IN_DIM;
    ushort* hh  = Fl + (size_t)N_OBJ * IN_DIM;            // [N_OBJ][HID]
    ushort* hl  = hh + (size_t)N_OBJ * HID;
    ushort* zpad = hl + (size_t)N_OBJ * HID;              // [1024] zeros
    int* eidx_all    = (int*)(zpad + 1024);
    int* level_nodes = eidx_all + N_OBJ;
    int* level_start = level_nodes + N_OBJ;

    build_levels<<<1, 1024, 0, stream>>>(parent_pos, level_nodes, level_start, zpad);
    xemb_kernel<<<dim3(NEMB, R5 / 256), 256, 0, stream>>>(
        embed_W, W_px, W_ioux, W_fx, b_px, b_ioux, b_iouh, b_fx, b_fh, Xemb);
    convert_wh<<<RH * HID / 1024, 256, 0, stream>>>(W_iouh, W_fh, Whh, Whl);
    convert_wx<<<R5 * IN_DIM / 1024, 256, 0, stream>>>(W_px, W_ioux, W_fx, Wxh, Wxl);
    convert_f<<<N_OBJ * IN_DIM / 1024, 256, 0, stream>>>(features, proc_order, Fh, Fl);

    xgemm_mfma<<<(N_OBJ / 128) * (R5 / 128), 256, 0, stream>>>(Fh, Fl, Wxh, Wxl, Hbuf);

    {
        const int* ls = level_start; const int* ln = level_nodes;
        const int* po = proc_order;  const int* pp = parent_pos;
        const ushort* whh = Whh; const ushort* whl = Whl;
        const ushort* zp = zpad; const float* xe = Xemb;
        const float* wo = W_out; const float* bo = b_out;
        float* hb = Hbuf; float* ca = c_all;
        ushort* hhp = hh; ushort* hlp = hl;
        int* ei = eidx_all; float* op = out;
        void* kargs[16] = { &ls, &ln, &po, &pp, &whh, &whl, &zp, &xe,
                            &wo, &bo, &hb, &ca, &hhp, &hlp, &ei, &op };
        hipError_t cerr = hipLaunchCooperativeKernel(
            (void*)level_loop, dim3(512), dim3(256), kargs, 0, stream);
        if (cerr != hipSuccess) {
            (void)hipGetLastError();   // clear sticky error, use fallback path
            for (int l = 0; l < MAXLVL; ++l) {
                if (l > 0)
                    hgemm_lvl<<<dim3(32, 64), 256, 0, stream>>>(
                        l, level_start, level_nodes, parent_pos,
                        hh, hl, Whh, Whl, zpad, Hbuf);
                gates_lvl<<<512, 256, 0, stream>>>(
                    l, level_start, level_nodes, proc_order, parent_pos,
                    Hbuf, Xemb, W_out, b_out, hh, hl, c_all, eidx_all, out);
            }
        }
    }
}

// Round 8
// 1322.168 us; speedup vs baseline: 3.1057x; 2.1849x over previous
//
#include <hip/hip_runtime.h>
#include <hip/hip_bf16.h>
#include <math.h>

#define N_OBJ 4096
#define IN_DIM 1024
#define EMB_D 200
#define HID 1024
#define NCLS 151
#define IN_SZ 1224      // IN_DIM + EMB_D
#define NEMB 152        // NCLS + 1 embedding rows
#define R5 5120         // px(1024) + iou(3072) + f(1024) pre-activation rows
#define RH 4096         // h-dependent rows (iou 3072 + f 1024)
#define MAXLVL 32

typedef __attribute__((ext_vector_type(8))) short bf16x8;
typedef __attribute__((ext_vector_type(4))) float f32x4;

__device__ __forceinline__ float sigf(float x) { return 1.f / (1.f + expf(-x)); }

// split fp32 into hi+lo bf16 (RNE both stages); hi+lo carries ~18 mantissa bits
__device__ __forceinline__ void split2(float x, ushort& hi, ushort& lo) {
    unsigned u = __float_as_uint(x);
    unsigned r = u + 0x7FFFu + ((u >> 16) & 1u);
    hi = (ushort)(r >> 16);
    float rem = x - __uint_as_float(r & 0xFFFF0000u);
    unsigned u2 = __float_as_uint(rem);
    unsigned r2 = u2 + 0x7FFFu + ((u2 >> 16) & 1u);
    lo = (ushort)(r2 >> 16);
}

// async global->LDS, 16B per lane; LDS dest must be wave-uniform base (+lane*16)
__device__ __forceinline__ void gload16(const ushort* src, ushort* dst) {
    __builtin_amdgcn_global_load_lds(
        (const __attribute__((address_space(1))) void*)src,
        (__attribute__((address_space(3))) void*)dst, 16, 0, 0);
}

// ---------------------------------------------------------------------------
// Kernel 1: depth per step, bucket steps by level; also zero zpad.
// ---------------------------------------------------------------------------
__global__ __launch_bounds__(1024)
void build_levels(const int* __restrict__ parent_pos,
                  int* __restrict__ level_nodes,
                  int* __restrict__ level_start,
                  ushort* __restrict__ zpad)
{
    __shared__ int dep[N_OBJ];
    __shared__ int par[N_OBJ];
    __shared__ int cnt[MAXLVL];
    __shared__ int offs[MAXLVL];
    __shared__ int base[MAXLVL + 1];
    __shared__ int done;
    const int tid = threadIdx.x;

    if (tid < 1024) zpad[tid] = 0;

    for (int t = tid; t < N_OBJ; t += 1024) {
        int p = parent_pos[t];
        par[t] = p;
        dep[t] = (p < 0) ? 0 : -1;
    }
    for (int l = tid; l < MAXLVL; l += 1024) { cnt[l] = 0; offs[l] = 0; }
    __syncthreads();

    for (int it = 0; it < 64; ++it) {
        if (tid == 0) done = 1;
        __syncthreads();
        for (int t = tid; t < N_OBJ; t += 1024) {
            if (dep[t] < 0) {
                int dp = dep[par[t]];
                if (dp >= 0) dep[t] = dp + 1;
                else done = 0;
            }
        }
        __syncthreads();
        int d = done;
        __syncthreads();
        if (d) break;
    }

    for (int t = tid; t < N_OBJ; t += 1024) {
        int d = dep[t];
        if (d < 0 || d >= MAXLVL) d = MAXLVL - 1;  // safety clamp
        dep[t] = d;
        atomicAdd(&cnt[d], 1);
    }
    __syncthreads();
    if (tid == 0) {
        base[0] = 0;
        for (int l = 0; l < MAXLVL; ++l) base[l + 1] = base[l] + cnt[l];
    }
    __syncthreads();
    for (int t = tid; t < N_OBJ; t += 1024) {
        int d = dep[t];
        int pos = base[d] + atomicAdd(&offs[d], 1);
        level_nodes[pos] = t;
    }
    for (int l = tid; l <= MAXLVL; l += 1024) level_start[l] = base[l];
}

// ---------------------------------------------------------------------------
// Kernel 2: Xemb[e][r] = W_row_r[:, 1024:1224] @ embed_W[e] + (all biases)
// ---------------------------------------------------------------------------
__global__ __launch_bounds__(256)
void xemb_kernel(const float* __restrict__ embed_W,
                 const float* __restrict__ W_px,
                 const float* __restrict__ W_ioux,
                 const float* __restrict__ W_fx,
                 const float* __restrict__ b_px,
                 const float* __restrict__ b_ioux,
                 const float* __restrict__ b_iouh,
                 const float* __restrict__ b_fx,
                 const float* __restrict__ b_fh,
                 float* __restrict__ Xemb)
{
    __shared__ float e_s[EMB_D];
    const int e = blockIdx.x;
    const int r = blockIdx.y * 256 + threadIdx.x;
    for (int k = threadIdx.x; k < EMB_D; k += 256) e_s[k] = embed_W[(size_t)e * EMB_D + k];
    __syncthreads();

    const float* wrow;
    float bias;
    if (r < HID) {
        wrow = W_px + (size_t)r * IN_SZ;
        bias = b_px[r];
    } else if (r < 4 * HID) {
        wrow = W_ioux + (size_t)(r - HID) * IN_SZ;
        bias = b_ioux[r - HID] + b_iouh[r - HID];
    } else {
        wrow = W_fx + (size_t)(r - 4 * HID) * IN_SZ;
        bias = b_fx[r - 4 * HID] + b_fh[r - 4 * HID];
    }

    float s = bias;
    for (int k = 0; k < EMB_D; ++k) s += wrow[IN_DIM + k] * e_s[k];
    Xemb[(size_t)e * R5 + r] = s;
}

// ---------------------------------------------------------------------------
// One-time split-conversion kernels (fp32 -> hi/lo bf16 pairs)
// ---------------------------------------------------------------------------
__global__ __launch_bounds__(256)
void convert_wh(const float* __restrict__ W_iouh, const float* __restrict__ W_fh,
                ushort* __restrict__ Whh, ushort* __restrict__ Whl)
{
    const int idx = (blockIdx.x * 256 + threadIdx.x) * 4;
    const int row = idx >> 10, k = idx & 1023;
    const float* src = (row < 3 * HID) ? (W_iouh + (size_t)row * HID + k)
                                       : (W_fh + (size_t)(row - 3 * HID) * HID + k);
    float4 v = *(const float4*)src;
    ushort4 hi, lo;
    split2(v.x, hi.x, lo.x); split2(v.y, hi.y, lo.y);
    split2(v.z, hi.z, lo.z); split2(v.w, hi.w, lo.w);
    *(ushort4*)(Whh + (size_t)row * HID + k) = hi;
    *(ushort4*)(Whl + (size_t)row * HID + k) = lo;
}

__global__ __launch_bounds__(256)
void convert_wx(const float* __restrict__ W_px, const float* __restrict__ W_ioux,
                const float* __restrict__ W_fx,
                ushort* __restrict__ Wxh, ushort* __restrict__ Wxl)
{
    const int idx = (blockIdx.x * 256 + threadIdx.x) * 4;
    const int row = idx >> 10, k = idx & 1023;
    const float* src;
    if (row < HID)          src = W_px   + (size_t)row * IN_SZ + k;
    else if (row < 4 * HID) src = W_ioux + (size_t)(row - HID) * IN_SZ + k;
    else                    src = W_fx   + (size_t)(row - 4 * HID) * IN_SZ + k;
    float4 v = *(const float4*)src;
    ushort4 hi, lo;
    split2(v.x, hi.x, lo.x); split2(v.y, hi.y, lo.y);
    split2(v.z, hi.z, lo.z); split2(v.w, hi.w, lo.w);
    *(ushort4*)(Wxh + (size_t)row * IN_DIM + k) = hi;
    *(ushort4*)(Wxl + (size_t)row * IN_DIM + k) = lo;
}

__global__ __launch_bounds__(256)
void convert_f(const float* __restrict__ features, const int* __restrict__ proc_order,
               ushort* __restrict__ Fh, ushort* __restrict__ Fl)
{
    const int idx = (blockIdx.x * 256 + threadIdx.x) * 4;
    const int t = idx >> 10, k = idx & 1023;
    const float* src = features + (size_t)proc_order[t] * IN_DIM + k;
    float4 v = *(const float4*)src;
    ushort4 hi, lo;
    split2(v.x, hi.x, lo.x); split2(v.y, hi.y, lo.y);
    split2(v.z, hi.z, lo.z); split2(v.w, hi.w, lo.w);
    *(ushort4*)(Fh + (size_t)t * IN_DIM + k) = hi;
    *(ushort4*)(Fl + (size_t)t * IN_DIM + k) = lo;
}

// ---------------------------------------------------------------------------
// Kernel 3 (ONCE): x-part GEMM via split-bf16 MFMA.
// global_load_lds staging (no staging VGPRs -> no spills), double-buffered
// BK=32, XOR-swizzled source + swizzled ds_read.
// ---------------------------------------------------------------------------
__global__ __launch_bounds__(256, 2)
void xgemm_mfma(const ushort* __restrict__ Fh, const ushort* __restrict__ Fl,
                const ushort* __restrict__ Wxh, const ushort* __restrict__ Wxl,
                float* __restrict__ Hbuf)
{
    const int bid = blockIdx.x;
    const int sup = bid >> 6, within = bid & 63;
    const int bm = (sup & 3) * 8 + (within & 7);
    const int bn = (sup >> 2) * 8 + (within >> 3);

    // 2 bufs x 4 matrices x 128 rows x 32 shorts = 65536 B
    __shared__ __align__(16) ushort smem[2][4][128 * 32];

    const int tid = threadIdx.x;
    const int lane = tid & 63;
    const int wid = tid >> 6;
    const int wm = wid & 1, wn = wid >> 1;
    const int g = lane >> 4;
    const int lr = lane >> 2, cg4 = lane & 3;

    const ushort* gsrc =
        (wid == 0) ? Fh  + (size_t)(bm * 128) * IN_DIM :
        (wid == 1) ? Fl  + (size_t)(bm * 128) * IN_DIM :
        (wid == 2) ? Wxh + (size_t)(bn * 128) * IN_DIM :
                     Wxl + (size_t)(bn * 128) * IN_DIM;

    f32x4 acc[4][4];
    #pragma unroll
    for (int i = 0; i < 4; ++i)
        #pragma unroll
        for (int j = 0; j < 4; ++j)
            acc[i][j] = (f32x4){0.f, 0.f, 0.f, 0.f};

    // prologue: stage chunk 0 into buf 0 (wave wid handles matrix wid)
    #pragma unroll
    for (int i = 0; i < 8; ++i) {
        int row = i * 16 + lr;
        int cs = (cg4 ^ ((row >> 1) & 3)) << 3;
        gload16(gsrc + (size_t)row * IN_DIM + cs, &smem[0][wid][i * 512]);
    }
    __syncthreads();

    int cur = 0;
    for (int kc = 0; kc < IN_DIM / 32; ++kc) {
        if (kc + 1 < IN_DIM / 32) {
            const int kt = (kc + 1) * 32;
            #pragma unroll
            for (int i = 0; i < 8; ++i) {
                int row = i * 16 + lr;
                int cs = (cg4 ^ ((row >> 1) & 3)) << 3;
                gload16(gsrc + (size_t)row * IN_DIM + kt + cs, &smem[cur ^ 1][wid][i * 512]);
            }
        }
        const ushort* Ahb = &smem[cur][0][0];
        const ushort* Alb = &smem[cur][1][0];
        const ushort* Bhb = &smem[cur][2][0];
        const ushort* Blb = &smem[cur][3][0];
        bf16x8 fa[8];
        #pragma unroll
        for (int mi = 0; mi < 4; ++mi) {
            int row = wm * 64 + mi * 16 + (lane & 15);
            int off = row * 32 + ((g ^ ((row >> 1) & 3)) << 3);
            fa[2 * mi]     = *(const bf16x8*)&Ahb[off];
            fa[2 * mi + 1] = *(const bf16x8*)&Alb[off];
        }
        #pragma unroll
        for (int ni = 0; ni < 4; ++ni) {
            int row = wn * 64 + ni * 16 + (lane & 15);
            int off = row * 32 + ((g ^ ((row >> 1) & 3)) << 3);
            bf16x8 fbh = *(const bf16x8*)&Bhb[off];
            bf16x8 fbl = *(const bf16x8*)&Blb[off];
            #pragma unroll
            for (int mi = 0; mi < 4; ++mi) {
                acc[mi][ni] = __builtin_amdgcn_mfma_f32_16x16x32_bf16(fa[2*mi],   fbh, acc[mi][ni], 0, 0, 0);
                acc[mi][ni] = __builtin_amdgcn_mfma_f32_16x16x32_bf16(fa[2*mi],   fbl, acc[mi][ni], 0, 0, 0);
                acc[mi][ni] = __builtin_amdgcn_mfma_f32_16x16x32_bf16(fa[2*mi+1], fbh, acc[mi][ni], 0, 0, 0);
            }
        }
        __syncthreads();   // drains vmcnt(0): next buffer ready, this buffer's reads done
        cur ^= 1;
    }

    // epilogue: LDS transpose (two 64-row passes) -> coalesced float4 writes
    float* Cs = (float*)&smem[0][0][0];   // [64][132] = 33792 B
    const int t0 = bm * 128, c0 = bn * 128;
    const int r4 = (lane >> 4) * 4;
    #pragma unroll
    for (int p = 0; p < 2; ++p) {
        if (wm == p) {
            #pragma unroll
            for (int mi = 0; mi < 4; ++mi)
                #pragma unroll
                for (int ni = 0; ni < 4; ++ni) {
                    int row = mi * 16 + r4;
                    int col = wn * 64 + ni * 16 + (lane & 15);
                    #pragma unroll
                    for (int r = 0; r < 4; ++r)
                        Cs[(row + r) * 132 + col] = acc[mi][ni][r];
                }
        }
        __syncthreads();
        #pragma unroll
        for (int i = 0; i < 8; ++i) {
            int row = i * 8 + (tid >> 5);
            float4 v = *(const float4*)&Cs[row * 132 + (tid & 31) * 4];
            *(float4*)&Hbuf[(size_t)(t0 + p * 64 + row) * R5 + c0 + (tid & 31) * 4] = v;
        }
        __syncthreads();
    }
}

// ---------------------------------------------------------------------------
// hgemm tile body: 64 nodes x 128 weight-rows, K=1024, split-bf16 MFMA,
// global_load_lds staging (A gathered per-lane by parent), BK=32 dbuf.
// ---------------------------------------------------------------------------
__device__ __forceinline__ void hgemm_tile(
    int s0, int n, int bm, int bn,
    const int* __restrict__ level_nodes, const int* __restrict__ parent_pos,
    const ushort* __restrict__ hh, const ushort* __restrict__ hl,
    const ushort* __restrict__ Whh, const ushort* __restrict__ Whl,
    const ushort* __restrict__ zpad, float* __restrict__ Hbuf,
    ushort* csm, int* s_node, int* s_par)
{
    const int tid = threadIdx.x;
    const int lane = tid & 63;
    const int wid = tid >> 6;
    const int wm = wid & 1, wn = wid >> 1;
    const int g = lane >> 4;
    const int lr = lane >> 2, cg4 = lane & 3;

    if (tid < 64) {
        int m = bm * 64 + tid;
        if (m < n) {
            int t = level_nodes[s0 + m];
            s_node[tid] = t;
            s_par[tid]  = parent_pos[t];
        } else { s_node[tid] = -1; s_par[tid] = -1; }
    }
    __syncthreads();

    f32x4 acc[2][4];
    #pragma unroll
    for (int i = 0; i < 2; ++i)
        #pragma unroll
        for (int j = 0; j < 4; ++j)
            acc[i][j] = (f32x4){0.f, 0.f, 0.f, 0.f};

    // buffer layout per buf (12288 shorts): [Ah 2048][Al 2048][Bh 4096][Bl 4096]
    auto stage = [&](int buf, int kt) {
        ushort* base = csm + buf * 12288;
        if (wid < 2) {
            const ushort* hsrc = (wid == 0) ? hh : hl;
            ushort* ld = base + wid * 2048;
            #pragma unroll
            for (int i = 0; i < 4; ++i) {
                int row = i * 16 + lr;
                int cs = (cg4 ^ ((row >> 1) & 3)) << 3;
                int par = s_par[row];
                const ushort* sp = (par >= 0) ? (hsrc + (size_t)par * HID + kt + cs)
                                              : (zpad + cs);
                gload16(sp, ld + i * 512);
            }
        } else {
            const ushort* wsrc = (wid == 2) ? Whh : Whl;
            ushort* ld = base + 4096 + (wid - 2) * 4096;
            #pragma unroll
            for (int i = 0; i < 8; ++i) {
                int row = i * 16 + lr;
                int cs = (cg4 ^ ((row >> 1) & 3)) << 3;
                gload16(wsrc + (size_t)(bn * 128 + row) * HID + kt + cs, ld + i * 512);
            }
        }
    };

    stage(0, 0);
    __syncthreads();
    int cur = 0;
    for (int kc = 0; kc < HID / 32; ++kc) {
        if (kc + 1 < HID / 32) stage(cur ^ 1, (kc + 1) * 32);
        const ushort* base = csm + cur * 12288;
        const ushort* Ahb = base;
        const ushort* Alb = base + 2048;
        const ushort* Bhb = base + 4096;
        const ushort* Blb = base + 8192;
        bf16x8 fa[4];
        #pragma unroll
        for (int mi = 0; mi < 2; ++mi) {
            int row = wm * 32 + mi * 16 + (lane & 15);
            int off = row * 32 + ((g ^ ((row >> 1) & 3)) << 3);
            fa[2 * mi]     = *(const bf16x8*)&Ahb[off];
            fa[2 * mi + 1] = *(const bf16x8*)&Alb[off];
        }
        #pragma unroll
        for (int ni = 0; ni < 4; ++ni) {
            int row = wn * 64 + ni * 16 + (lane & 15);
            int off = row * 32 + ((g ^ ((row >> 1) & 3)) << 3);
            bf16x8 fbh = *(const bf16x8*)&Bhb[off];
            bf16x8 fbl = *(const bf16x8*)&Blb[off];
            #pragma unroll
            for (int mi = 0; mi < 2; ++mi) {
                acc[mi][ni] = __builtin_amdgcn_mfma_f32_16x16x32_bf16(fa[2*mi],   fbh, acc[mi][ni], 0, 0, 0);
                acc[mi][ni] = __builtin_amdgcn_mfma_f32_16x16x32_bf16(fa[2*mi],   fbl, acc[mi][ni], 0, 0, 0);
                acc[mi][ni] = __builtin_amdgcn_mfma_f32_16x16x32_bf16(fa[2*mi+1], fbh, acc[mi][ni], 0, 0, 0);
            }
        }
        __syncthreads();
        cur ^= 1;
    }

    // epilogue: LDS transpose -> coalesced float4 RMW
    float* Cs = (float*)csm;   // [64][132] = 33792 B
    const int r4 = (lane >> 4) * 4;
    #pragma unroll
    for (int mi = 0; mi < 2; ++mi)
        #pragma unroll
        for (int ni = 0; ni < 4; ++ni) {
            int row = wm * 32 + mi * 16 + r4;
            int col = wn * 64 + ni * 16 + (lane & 15);
            #pragma unroll
            for (int r = 0; r < 4; ++r)
                Cs[(row + r) * 132 + col] = acc[mi][ni][r];
        }
    __syncthreads();
    #pragma unroll
    for (int i = 0; i < 8; ++i) {
        int row = i * 8 + (tid >> 5);
        if (bm * 64 + row < n) {
            int t = s_node[row];
            float* dst = Hbuf + (size_t)t * R5 + HID + bn * 128 + (tid & 31) * 4;
            float4 o = *(const float4*)dst;
            const float* cp = &Cs[row * 132 + (tid & 31) * 4];
            o.x += cp[0]; o.y += cp[1]; o.z += cp[2]; o.w += cp[3];
            *(float4*)dst = o;
        }
    }
}

// ---------------------------------------------------------------------------
// gates + dist body for one node (256 threads). hs = 1024 floats of LDS.
// ---------------------------------------------------------------------------
__device__ __forceinline__ void gates_dist_node(
    int t,
    const int* __restrict__ proc_order, const int* __restrict__ parent_pos,
    const float* __restrict__ Hbuf, const float* __restrict__ Xemb,
    const float* __restrict__ W_out, const float* __restrict__ b_out,
    ushort* __restrict__ hh, ushort* __restrict__ hl,
    float* __restrict__ c_all, int* __restrict__ eidx_all, float* __restrict__ out,
    float* hs, float* bv_s, int* bi_s)
{
    const int tid = threadIdx.x;
    const int pid = parent_pos[t];
    const int eidx = (pid < 0) ? 0 : eidx_all[pid];

    const float4* H4 = (const float4*)(Hbuf + (size_t)t * R5);
    const float4* E4 = (const float4*)(Xemb + (size_t)eidx * R5);

    float4 Hpx = H4[tid],        Epx = E4[tid];
    float4 Hi  = H4[256 + tid],  Ei  = E4[256 + tid];
    float4 Ho  = H4[512 + tid],  Eo  = E4[512 + tid];
    float4 Hu  = H4[768 + tid],  Eu  = E4[768 + tid];
    float4 Hf  = H4[1024 + tid], Ef  = E4[1024 + tid];
    float4 PC = (pid < 0) ? make_float4(0.f, 0.f, 0.f, 0.f)
                          : ((const float4*)(c_all + (size_t)pid * HID))[tid];

    float cv[4], hv[4];
#define GATE(CP, IDX) { \
    float pxv = Hpx.CP + Epx.CP; \
    float iv  = Hi.CP + Ei.CP; \
    float ov  = Ho.CP + Eo.CP; \
    float uv  = Hu.CP + Eu.CP; \
    float fv  = Hf.CP + Ef.CP; \
    float ig = sigf(iv), og = sigf(ov), ug = tanhf(uv), fg = sigf(fv); \
    float cc = ig * ug + fg * PC.CP; \
    cv[IDX] = cc; \
    hv[IDX] = og * tanhf(cc) * sigf(pxv); }
    GATE(x, 0) GATE(y, 1) GATE(z, 2) GATE(w, 3)
#undef GATE

    float4 c4 = make_float4(cv[0], cv[1], cv[2], cv[3]);
    float4 h4 = make_float4(hv[0], hv[1], hv[2], hv[3]);
    ((float4*)(c_all + (size_t)t * HID))[tid] = c4;
    ((float4*)hs)[tid] = h4;
    ushort4 shi, slo;
    split2(h4.x, shi.x, slo.x); split2(h4.y, shi.y, slo.y);
    split2(h4.z, shi.z, slo.z); split2(h4.w, shi.w, slo.w);
    *(ushort4*)(hh + (size_t)t * HID + (tid << 2)) = shi;
    *(ushort4*)(hl + (size_t)t * HID + (tid << 2)) = slo;
    __syncthreads();

    const int node = proc_order[t];
    float* dists = out + (size_t)node * NCLS;
    const int wave = tid >> 6, lane = tid & 63;

    float bv = -3.4e38f; int bi = NCLS;
    for (int r = wave; r < NCLS; r += 4) {
        const float* wr = W_out + (size_t)r * HID;
        float s = 0.f;
        #pragma unroll
        for (int q = 0; q < 4; ++q) {
            float4 w4 = *(const float4*)(wr + (lane << 2) + q * 256);
            float4 x4 = *(const float4*)(hs + (lane << 2) + q * 256);
            s += w4.x * x4.x + w4.y * x4.y + w4.z * x4.z + w4.w * x4.w;
        }
        #pragma unroll
        for (int off = 32; off > 0; off >>= 1) s += __shfl_down(s, off, 64);
        if (lane == 0) {
            s += b_out[r];
            dists[r] = s;
            if (r >= 1 && s > bv) { bv = s; bi = r; }
        }
    }
    if (lane == 0) { bv_s[wave] = bv; bi_s[wave] = bi; }
    __syncthreads();
    if (tid == 0) {
        float v = bv_s[0]; int b = bi_s[0];
        for (int w = 1; w < 4; ++w)
            if (bv_s[w] > v || (bv_s[w] == v && bi_s[w] < b)) { v = bv_s[w]; b = bi_s[w]; }
        eidx_all[t] = b + 1;
        out[(size_t)N_OBJ * NCLS + node] = (float)b;
    }
    __syncthreads();   // hs / bv_s reused by next node
}

// ---------------------------------------------------------------------------
// Per-level kernels (chain; kernel boundary = global barrier).
// ---------------------------------------------------------------------------
__global__ __launch_bounds__(256, 2)
void hgemm_lvl(int lvl, const int* __restrict__ level_start,
               const int* __restrict__ level_nodes, const int* __restrict__ parent_pos,
               const ushort* __restrict__ hh, const ushort* __restrict__ hl,
               const ushort* __restrict__ Whh, const ushort* __restrict__ Whl,
               const ushort* __restrict__ zpad, float* __restrict__ Hbuf)
{
    __shared__ __align__(16) ushort csm[24576];
    __shared__ int s_node[64], s_par[64];
    const int s0 = level_start[lvl];
    const int n  = level_start[lvl + 1] - s0;
    const int bm = blockIdx.y;
    if (bm * 64 >= n) return;      // uniform exit before any barrier
    hgemm_tile(s0, n, bm, blockIdx.x, level_nodes, parent_pos,
               hh, hl, Whh, Whl, zpad, Hbuf, csm, s_node, s_par);
}

__global__ __launch_bounds__(256, 2)
void gates_lvl(int lvl, const int* __restrict__ level_start,
               const int* __restrict__ level_nodes, const int* __restrict__ proc_order,
               const int* __restrict__ parent_pos,
               const float* __restrict__ Hbuf, const float* __restrict__ Xemb,
               const float* __restrict__ W_out, const float* __restrict__ b_out,
               ushort* __restrict__ hh, ushort* __restrict__ hl,
               float* __restrict__ c_all, int* __restrict__ eidx_all,
               float* __restrict__ out)
{
    __shared__ __align__(16) float hs[HID];
    __shared__ float bv_s[4];
    __shared__ int bi_s[4];
    const int s0 = level_start[lvl];
    const int n  = level_start[lvl + 1] - s0;
    for (int slot = blockIdx.x; slot < n; slot += gridDim.x) {
        int t = level_nodes[s0 + slot];
        gates_dist_node(t, proc_order, parent_pos, Hbuf, Xemb, W_out, b_out,
                        hh, hl, c_all, eidx_all, out, hs, bv_s, bi_s);
    }
}

// ---------------------------------------------------------------------------
extern "C" void kernel_launch(void* const* d_in, const int* in_sizes, int n_in,
                              void* d_out, int out_size, void* d_ws, size_t ws_size,
                              hipStream_t stream)
{
    const float* features = (const float*)d_in[0];
    const float* embed_W  = (const float*)d_in[1];
    const float* W_px     = (const float*)d_in[2];
    const float* b_px     = (const float*)d_in[3];
    const float* W_ioux   = (const float*)d_in[4];
    const float* b_ioux   = (const float*)d_in[5];
    const float* W_iouh   = (const float*)d_in[6];
    const float* b_iouh   = (const float*)d_in[7];
    const float* W_fx     = (const float*)d_in[8];
    const float* b_fx     = (const float*)d_in[9];
    const float* W_fh     = (const float*)d_in[10];
    const float* b_fh     = (const float*)d_in[11];
    const float* W_out    = (const float*)d_in[12];
    const float* b_out    = (const float*)d_in[13];
    const int* proc_order = (const int*)d_in[14];
    const int* parent_pos = (const int*)d_in[15];
    float* out = (float*)d_out;

    // workspace layout (~175 MB)
    float* Hbuf  = (float*)d_ws;                          // [N_OBJ][R5]
    float* c_all = Hbuf + (size_t)N_OBJ * R5;             // [N_OBJ][HID]
    float* Xemb  = c_all + (size_t)N_OBJ * HID;           // [NEMB][R5]
    ushort* Whh = (ushort*)(Xemb + (size_t)NEMB * R5);    // [RH][HID]
    ushort* Whl = Whh + (size_t)RH * HID;
    ushort* Wxh = Whl + (size_t)RH * HID;                 // [R5][IN_DIM]
    ushort* Wxl = Wxh + (size_t)R5 * IN_DIM;
    ushort* Fh  = Wxl + (size_t)R5 * IN_DIM;              // [N_OBJ][IN_DIM]
    ushort* Fl  = Fh + (size_t)N_OBJ * IN_DIM;
    ushort* hh  = Fl + (size_t)N_OBJ * IN_DIM;            // [N_OBJ][HID]
    ushort* hl  = hh + (size_t)N_OBJ * HID;
    ushort* zpad = hl + (size_t)N_OBJ * HID;              // [1024] zeros
    int* eidx_all    = (int*)(zpad + 1024);
    int* level_nodes = eidx_all + N_OBJ;
    int* level_start = level_nodes + N_OBJ;

    build_levels<<<1, 1024, 0, stream>>>(parent_pos, level_nodes, level_start, zpad);
    xemb_kernel<<<dim3(NEMB, R5 / 256), 256, 0, stream>>>(
        embed_W, W_px, W_ioux, W_fx, b_px, b_ioux, b_iouh, b_fx, b_fh, Xemb);
    convert_wh<<<RH * HID / 1024, 256, 0, stream>>>(W_iouh, W_fh, Whh, Whl);
    convert_wx<<<R5 * IN_DIM / 1024, 256, 0, stream>>>(W_px, W_ioux, W_fx, Wxh, Wxl);
    convert_f<<<N_OBJ * IN_DIM / 1024, 256, 0, stream>>>(features, proc_order, Fh, Fl);

    xgemm_mfma<<<(N_OBJ / 128) * (R5 / 128), 256, 0, stream>>>(Fh, Fl, Wxh, Wxl, Hbuf);

    for (int l = 0; l < MAXLVL; ++l) {
        if (l > 0)
            hgemm_lvl<<<dim3(32, 64), 256, 0, stream>>>(
                l, level_start, level_nodes, parent_pos,
                hh, hl, Whh, Whl, zpad, Hbuf);
        gates_lvl<<<512, 256, 0, stream>>>(
            l, level_start, level_nodes, proc_order, parent_pos,
            Hbuf, Xemb, W_out, b_out, hh, hl, c_all, eidx_all, out);
    }
}